// Round 17
// baseline (470.232 us; speedup 1.0000x reference)
//
#include <hip/hip_runtime.h>
#include <hip/hip_bf16.h>
#include <math.h>

#define B_ 256
#define S_ 512
#define H_ 256
#define D_ 512

typedef __bf16 bf16;
typedef __bf16 bf16x8 __attribute__((ext_vector_type(8)));
typedef float  f32x4  __attribute__((ext_vector_type(4)));
typedef unsigned short u16x8 __attribute__((ext_vector_type(8)));
typedef unsigned short u16x4 __attribute__((ext_vector_type(4)));

#define MFMA(a, b, c) __builtin_amdgcn_mfma_f32_16x16x32_bf16((a), (b), (c), 0, 0, 0)

// 128B-row-stride bf16 tiles: XOR-swizzle 16B slot with row&7 (involution).
__device__ __forceinline__ int swz(int row, int kbyte) {
  return (row * 128 + kbyte) ^ ((row & 7) << 4);
}
__device__ __forceinline__ unsigned short bfbits(float f) {
  bf16 h = (bf16)f;
  union { bf16 b; unsigned short u; } c; c.b = h; return c.u;
}
__device__ __forceinline__ bf16x8 cvt8(const float* __restrict__ p) {
  f32x4 a = *(const f32x4*)p;
  f32x4 b = *(const f32x4*)(p + 4);
  bf16x8 r;
  r[0] = (bf16)a[0]; r[1] = (bf16)a[1]; r[2] = (bf16)a[2]; r[3] = (bf16)a[3];
  r[4] = (bf16)b[0]; r[5] = (bf16)b[1]; r[6] = (bf16)b[2]; r[7] = (bf16)b[3];
  return r;
}
__device__ __forceinline__ void gload16(const unsigned short* g, unsigned char* l) {
  __builtin_amdgcn_global_load_lds(
      (const __attribute__((address_space(1))) unsigned int*)g,
      (__attribute__((address_space(3))) unsigned int*)l, 16, 0, 0);
}

// ---------------------------------------------------------------------------
// Weight conversion. Writes wc PRE-SWIZZLED (rule #21) so linear
// global_load_lds staging + swz() LDS read is bank-conflict-free.
// ---------------------------------------------------------------------------
__global__ __launch_bounds__(256) void k_convw(
    const float* __restrict__ kw, const float* __restrict__ qw,
    const float* __restrict__ vw, unsigned short* __restrict__ wc)
{
  const int r = blockIdx.x;
  const float* src = (r < 256) ? kw + (size_t)r * 512
                   : (r < 512) ? qw + (size_t)(r - 256) * 512
                               : vw + (size_t)(r - 512) * 512;
#pragma unroll
  for (int q = 0; q < 2; ++q) {
    const int c = threadIdx.x * 2 + q;
    const int sc = (c & ~63) | (((((c >> 3) & 7) ^ (r & 7))) << 3) | (c & 7);
    wc[(size_t)r * 512 + c] = bfbits(src[sc]);
  }
}

// ---------------------------------------------------------------------------
// Kernel 1: QKV projection (r16 version: r13 structure + LDS-transpose
// epilogues for k/q and v — all stores coalesced u16x8).
// ---------------------------------------------------------------------------
__global__ __launch_bounds__(256, 2) void k_proj6(
    const float* __restrict__ x,
    const unsigned short* __restrict__ wc,
    const float* __restrict__ kbi, const float* __restrict__ qbi,
    const float* __restrict__ vbi,
    unsigned short* __restrict__ k_t, unsigned short* __restrict__ q_t,
    unsigned short* __restrict__ v_o, int nwg)
{
  __shared__ __align__(16) unsigned char sA[32768];  // 128 m x 16 fp32-slots
  __shared__ __align__(16) unsigned char sB[32768];  // 256 n x 64 k bf16

  const int o = blockIdx.x;
  const int cpx = nwg >> 3;
  const int a = (o & 7) * cpx + (o >> 3);
  const int mt = a / 3;
  const int region = a - mt * 3;
  const int m0 = mt * 128;
  const int w0 = region * 256;
  const float* __restrict__ Bi = (region == 0) ? kbi : (region == 1) ? qbi : vbi;

  const int tid = threadIdx.x;
  const int lane = tid & 63;
  const int wid = tid >> 6;
  const int wm = wid >> 1;
  const int wn = wid & 1;
  const int l15 = lane & 15;
  const int l16 = lane >> 4;
  const int lr8 = lane >> 3;
  const int lk8 = (lane & 7) << 3;
  const int ar4 = lane >> 4;
  const int aslot = l15;

  f32x4 acc[4][8];
#pragma unroll
  for (int i = 0; i < 4; ++i)
#pragma unroll
    for (int j = 0; j < 8; ++j) acc[i][j] = (f32x4){0.f, 0.f, 0.f, 0.f};

  for (int kt = 0; kt < 8; ++kt) {
    if (kt) __syncthreads();
#pragma unroll
    for (int i = 0; i < 8; ++i) {
      const int chunk = wid * 8 + i;
      const int arow = chunk * 4 + ar4;
      const int gslot = aslot ^ (arow & 7);
      gload16((const unsigned short*)(
                  x + (size_t)(m0 + arow) * D_ + kt * 64 + gslot * 4),
              sA + chunk * 1024);
    }
#pragma unroll
    for (int i = 0; i < 8; ++i) {
      const int chunk = wid * 8 + i;
      const int row = chunk * 8 + lr8;
      gload16(wc + (size_t)(w0 + row) * 512 + kt * 64 + lk8, sB + chunk * 1024);
    }
    __syncthreads();
#pragma unroll
    for (int ks = 0; ks < 2; ++ks) {
      const int kb2 = ks * 64 + (l16 << 4);
      const int sbase2 = ks * 8 + l16 * 2;
      bf16x8 av[4], bv[8];
#pragma unroll
      for (int f = 0; f < 4; ++f) {
        const int row = wm * 64 + f * 16 + l15;
        const int sw = row & 7;
        const unsigned char* pr = sA + row * 256;
        f32x4 lo = *(const f32x4*)(pr + ((sbase2 ^ sw) << 4));
        f32x4 hi = *(const f32x4*)(pr + (((sbase2 + 1) ^ sw) << 4));
        bf16x8 r;
        r[0] = (bf16)lo[0]; r[1] = (bf16)lo[1];
        r[2] = (bf16)lo[2]; r[3] = (bf16)lo[3];
        r[4] = (bf16)hi[0]; r[5] = (bf16)hi[1];
        r[6] = (bf16)hi[2]; r[7] = (bf16)hi[3];
        av[f] = r;
      }
#pragma unroll
      for (int f = 0; f < 8; ++f)
        bv[f] = *(const bf16x8*)(sB + swz(wn * 128 + f * 16 + l15, kb2));
#pragma unroll
      for (int fm = 0; fm < 4; ++fm)
#pragma unroll
        for (int fn = 0; fn < 8; ++fn)
          acc[fm][fn] = MFMA(av[fm], bv[fn], acc[fm][fn]);
    }
  }

  const int b = m0 >> 9;
  const int sbase = m0 & 511;

  if (region < 2) {
    // k/q: LDS transpose (sB dead) -> coalesced u16x8 stores along s.
    unsigned short* outp = (region == 0) ? k_t : q_t;
#pragma unroll
    for (int wmr = 0; wmr < 2; ++wmr) {
      __syncthreads();
      if (wm == wmr) {
#pragma unroll
        for (int fn = 0; fn < 8; ++fn) {
          const int hcol = wn * 128 + fn * 16 + l15;
          const float bias = Bi[hcol];
#pragma unroll
          for (int fm = 0; fm < 4; ++fm) {
            u16x4 ov;
#pragma unroll
            for (int j = 0; j < 4; ++j) ov[j] = bfbits(acc[fm][fn][j] + bias);
            const int byteoff = (fm * 32 + l16 * 8) ^ ((hcol & 7) << 4);
            *(u16x4*)(sB + hcol * 128 + byteoff) = ov;
          }
        }
      }
      __syncthreads();
#pragma unroll
      for (int c = 0; c < 8; ++c) {
        const int idx = c * 256 + tid;
        const int hcol = idx >> 3;
        const int sslot = idx & 7;
        const int byteoff = (sslot * 16) ^ ((hcol & 7) << 4);
        u16x8 v = *(const u16x8*)(sB + hcol * 128 + byteoff);
        *(u16x8*)(outp + (size_t)b * (H_ * S_) + (size_t)hcol * S_ +
                  sbase + wmr * 64 + sslot * 8) = v;
      }
    }
  } else {
    // v: LDS transpose (sB dead) -> coalesced u16x8 row stores.
    unsigned short* sT = (unsigned short*)sB;    // [32 rows][256 h]
#pragma unroll
    for (int fm = 0; fm < 4; ++fm) {
      __syncthreads();
#pragma unroll
      for (int fn = 0; fn < 8; ++fn) {
        const int hcol = wn * 128 + fn * 16 + l15;
        const float bias = Bi[hcol];
#pragma unroll
        for (int j = 0; j < 4; ++j) {
          const int tr = wm * 16 + l16 * 4 + j;
          sT[tr * 256 + hcol] = bfbits(acc[fm][fn][j] + bias);
        }
      }
      __syncthreads();
#pragma unroll
      for (int c = 0; c < 4; ++c) {
        const int idx = c * 256 + tid;
        const int tr = idx >> 5;
        const int hc = (idx & 31) * 8;
        const int s = sbase + (tr >> 4) * 64 + fm * 16 + (tr & 15);
        *(u16x8*)(v_o + (size_t)b * (S_ * H_) + (size_t)s * H_ + hc) =
            *(const u16x8*)(sT + tr * 256 + hc);
      }
    }
  }
}

// ---------------------------------------------------------------------------
// Kernel 2: fused scores+softmax+PV+bias+LN+GELU. Phase 1 unchanged
// (staged K/Q, counted vmcnt). Phase 2 REBUILT: V fragments load
// global->VGPR directly (identical element mapping to the old staged path,
// involution-verified), deleting ALL phase-2 staging barriers and the
// 16-step vmcnt chain; the kh-loop is now compiler-pipelineable and
// overlaps across the 4 waves/SIMD. lbuf moves to the freed sV region.
// ---------------------------------------------------------------------------
__global__ __launch_bounds__(1024, 4) void k_attn(
    const unsigned short* __restrict__ k_t,
    const unsigned short* __restrict__ q_t,
    const unsigned short* __restrict__ v_o,
    const float* __restrict__ attn_bias,
    const float* __restrict__ lng, const float* __restrict__ lnb,
    unsigned short* __restrict__ act)
{
  __shared__ __align__(16) unsigned char sm[163840];
  unsigned char* sP = sm;                       // 128 KB P[256 g][256 h] (after p1)
  float* redm = (float*)(sm + 131072);          // [4][256]
  float* reds = (float*)(sm + 131072 + 4096);   // [4][256]
  float* lbuf = (float*)(sm + 131072);          // epilogue (region reused)

  const int tid = threadIdx.x;
  const int lane = tid & 63;
  const int wid = tid >> 6;           // 0..15
  const int l15 = lane & 15;
  const int l16 = lane >> 4;          // 0..3
  const int b = blockIdx.x;
  const int wh = wid >> 2;            // 0..3: h-quarter (p1) / s-quarter (p2)
  const int wq = wid & 3;             // 0..3: g-quarter

  const unsigned short* __restrict__ Kb = k_t + (size_t)b * (H_ * S_);
  const unsigned short* __restrict__ Qb = q_t + (size_t)b * (H_ * S_);
  const unsigned short* __restrict__ Vb = v_o + (size_t)b * (S_ * H_);

  // ---- Phase 1: S = K . Q^T, dbuf staging in sm[0:128K] ----
  const int srow8 = lane >> 3;
  const int scol16 = (lane & 7) ^ srow8;        // pre-swizzled source col

  auto stage1 = [&](int t, int buf) {           // 4 gload16/thread
#pragma unroll
    for (int i = 0; i < 2; ++i) {
      const int cb = wid * 2 + i;
      const int row = cb * 8 + srow8;
      gload16(Kb + (size_t)row * S_ + t * 64 + scol16 * 8,
              sm + buf * 65536 + cb * 1024);
      gload16(Qb + (size_t)row * S_ + t * 64 + scol16 * 8,
              sm + buf * 65536 + 32768 + cb * 1024);
    }
  };

  f32x4 acc1[4][4];
#pragma unroll
  for (int i = 0; i < 4; ++i)
#pragma unroll
    for (int j = 0; j < 4; ++j) acc1[i][j] = (f32x4){0.f, 0.f, 0.f, 0.f};

  stage1(0, 0);
  for (int t = 0; t < 8; ++t) {
    const int cur = t & 1;
    if (t < 7) stage1(t + 1, cur ^ 1);
    if (t < 7) asm volatile("s_waitcnt vmcnt(4)" ::: "memory");
    else       asm volatile("s_waitcnt vmcnt(0)" ::: "memory");
    __builtin_amdgcn_s_barrier();
    __builtin_amdgcn_sched_barrier(0);
    const unsigned char* sK = sm + cur * 65536;
    const unsigned char* sQ = sK + 32768;
#pragma unroll
    for (int ks = 0; ks < 2; ++ks) {
      const int kb2 = ks * 64 + l16 * 16;
      bf16x8 av[4], bv[4];
#pragma unroll
      for (int f = 0; f < 4; ++f)
        av[f] = *(const bf16x8*)(sK + swz(wh * 64 + f * 16 + l15, kb2));
#pragma unroll
      for (int f = 0; f < 4; ++f)
        bv[f] = *(const bf16x8*)(sQ + swz(wq * 64 + f * 16 + l15, kb2));
#pragma unroll
      for (int fm = 0; fm < 4; ++fm)
#pragma unroll
        for (int fn = 0; fn < 4; ++fn)
          acc1[fm][fn] = MFMA(av[fm], bv[fn], acc1[fm][fn]);
    }
    __builtin_amdgcn_sched_barrier(0);
    __builtin_amdgcn_s_barrier();               // reads consumed before overwrite
  }

  // ---- column softmax over h ----
  float cmax[4] = {-3.0e38f, -3.0e38f, -3.0e38f, -3.0e38f};
#pragma unroll
  for (int fm = 0; fm < 4; ++fm)
#pragma unroll
    for (int fn = 0; fn < 4; ++fn)
#pragma unroll
      for (int j = 0; j < 4; ++j) {
        acc1[fm][fn][j] *= 0.0625f;
        cmax[fn] = fmaxf(cmax[fn], acc1[fm][fn][j]);
      }
#pragma unroll
  for (int fn = 0; fn < 4; ++fn) {
    cmax[fn] = fmaxf(cmax[fn], __shfl_xor(cmax[fn], 16));
    cmax[fn] = fmaxf(cmax[fn], __shfl_xor(cmax[fn], 32));
  }
  if (lane < 16) {
#pragma unroll
    for (int fn = 0; fn < 4; ++fn)
      redm[wh * 256 + wq * 64 + fn * 16 + lane] = cmax[fn];
  }
  __syncthreads();
  float gmax[4];
#pragma unroll
  for (int fn = 0; fn < 4; ++fn) {
    const int c = wq * 64 + fn * 16 + l15;
    gmax[fn] = fmaxf(fmaxf(redm[c], redm[256 + c]),
                     fmaxf(redm[512 + c], redm[768 + c]));
  }
  float csum[4] = {0.f, 0.f, 0.f, 0.f};
#pragma unroll
  for (int fm = 0; fm < 4; ++fm)
#pragma unroll
    for (int fn = 0; fn < 4; ++fn)
#pragma unroll
      for (int j = 0; j < 4; ++j) {
        float p = __expf(acc1[fm][fn][j] - gmax[fn]);
        acc1[fm][fn][j] = p;
        csum[fn] += p;
      }
#pragma unroll
  for (int fn = 0; fn < 4; ++fn) {
    csum[fn] += __shfl_xor(csum[fn], 16);
    csum[fn] += __shfl_xor(csum[fn], 32);
  }
  if (lane < 16) {
#pragma unroll
    for (int fn = 0; fn < 4; ++fn)
      reds[wh * 256 + wq * 64 + fn * 16 + lane] = csum[fn];
  }
  __syncthreads();
  float gi[4];
#pragma unroll
  for (int fn = 0; fn < 4; ++fn) {
    const int c = wq * 64 + fn * 16 + l15;
    gi[fn] = 1.0f / (reds[c] + reds[256 + c] + reds[512 + c] + reds[768 + c]);
  }

  // ---- write P[g][h] bf16, swizzled, over the (dead) staging buffers ----
#pragma unroll
  for (int fn = 0; fn < 4; ++fn) {
    const int g = wq * 64 + fn * 16 + l15;
#pragma unroll
    for (int fm = 0; fm < 4; ++fm) {
      const int h0 = wh * 64 + fm * 16 + l16 * 4;
      u16x4 pv;
#pragma unroll
      for (int j = 0; j < 4; ++j) pv[j] = bfbits(acc1[fm][fn][j] * gi[fn]);
      *(u16x4*)(sP + ((g * 512 + h0 * 2) ^ ((g & 7) << 4))) = pv;
    }
  }
  __syncthreads();                              // P visible to all

  // ---- Phase 2: out = V . P^T, V fragments DIRECT from global ----
  for (int so = 0; so < 2; ++so) {
    f32x4 acc2[4][4];
#pragma unroll
    for (int i = 0; i < 4; ++i)
#pragma unroll
      for (int j = 0; j < 4; ++j) acc2[i][j] = (f32x4){0.f, 0.f, 0.f, 0.f};

#pragma unroll
    for (int kh = 0; kh < 8; ++kh) {
      bf16x8 av[4], bv[4];
#pragma unroll
      for (int f = 0; f < 4; ++f)
        av[f] = *(const bf16x8*)(
            Vb + (size_t)(so * 256 + wh * 64 + f * 16 + l15) * H_ +
            kh * 32 + l16 * 8);
#pragma unroll
      for (int fn = 0; fn < 4; ++fn) {
        const int g = wq * 64 + fn * 16 + l15;
        bv[fn] = *(const bf16x8*)(
            sP + ((g * 512 + kh * 64 + l16 * 16) ^ ((g & 7) << 4)));
      }
#pragma unroll
      for (int f = 0; f < 4; ++f)
#pragma unroll
        for (int fn = 0; fn < 4; ++fn)
          acc2[f][fn] = MFMA(av[f], bv[fn], acc2[f][fn]);
    }

    // epilogue: +bias, LN over g (cross-wave via lbuf), GELU, store
    __syncthreads();                            // lbuf region free (redm dead)
#pragma unroll
    for (int f = 0; f < 4; ++f) {
#pragma unroll
      for (int j = 0; j < 4; ++j) {
        const int rloc = wh * 64 + f * 16 + l16 * 4 + j;
        const int s = so * 256 + rloc;
        float ps = 0.f, psq = 0.f;
#pragma unroll
        for (int fn = 0; fn < 4; ++fn) {
          const int g = wq * 64 + fn * 16 + l15;
          float vv = acc2[f][fn][j] + attn_bias[(size_t)s * H_ + g];
          acc2[f][fn][j] = vv;
          ps += vv; psq += vv * vv;
        }
        ps += __shfl_xor(ps, 1);  psq += __shfl_xor(psq, 1);
        ps += __shfl_xor(ps, 2);  psq += __shfl_xor(psq, 2);
        ps += __shfl_xor(ps, 4);  psq += __shfl_xor(psq, 4);
        ps += __shfl_xor(ps, 8);  psq += __shfl_xor(psq, 8);
        if (l15 == 0) {
          lbuf[wq * 256 + rloc] = ps;
          lbuf[1024 + wq * 256 + rloc] = psq;
        }
      }
    }
    __syncthreads();
#pragma unroll
    for (int f = 0; f < 4; ++f) {
#pragma unroll
      for (int j = 0; j < 4; ++j) {
        const int rloc = wh * 64 + f * 16 + l16 * 4 + j;
        const int s = so * 256 + rloc;
        float sum = lbuf[rloc] + lbuf[256 + rloc] +
                    lbuf[512 + rloc] + lbuf[768 + rloc];
        float sq  = lbuf[1024 + rloc] + lbuf[1280 + rloc] +
                    lbuf[1536 + rloc] + lbuf[1792 + rloc];
        float mu = sum * (1.f / H_);
        float var = sq * (1.f / H_) - mu * mu;
        float rstd = rsqrtf(var + 1e-5f);
#pragma unroll
        for (int fn = 0; fn < 4; ++fn) {
          const int g = wq * 64 + fn * 16 + l15;
          float xv = (acc2[f][fn][j] - mu) * rstd * lng[g] + lnb[g];
          float y = 0.5f * xv * (1.f + erff(xv * 0.70710678118654752f));
          act[(size_t)b * (S_ * H_) + (size_t)s * H_ + g] = bfbits(y);
        }
      }
    }
  }
}

// ---------------------------------------------------------------------------
// Kernel 3: final GEMM, split-K (unchanged from r13 — near HBM floor).
// ---------------------------------------------------------------------------
__global__ __launch_bounds__(512, 4) void k_final2(
    const unsigned short* __restrict__ act,
    const float* __restrict__ ow,
    float* __restrict__ partial)
{
  __shared__ __align__(16) unsigned char sA[32768];  // 256 m x 8 bf16-slots
  __shared__ __align__(16) unsigned char sB[16384];  // 64 n x 16 fp32-slots

  const int tid = threadIdx.x;
  const int lane = tid & 63;
  const int wid = tid >> 6;
  const int wm = wid >> 1;
  const int wn = wid & 1;
  const int l15 = lane & 15;
  const int l16 = lane >> 4;
  const int n0 = blockIdx.x * 64;
  const size_t k0 = (size_t)blockIdx.y * 4096;

  f32x4 acc[4][2];
#pragma unroll
  for (int i = 0; i < 4; ++i)
#pragma unroll
    for (int j = 0; j < 2; ++j) acc[i][j] = (f32x4){0.f, 0.f, 0.f, 0.f};

  for (int kt = 0; kt < 64; ++kt) {
    const size_t kb = k0 + kt * 64;
    if (kt) __syncthreads();
#pragma unroll
    for (int i = 0; i < 4; ++i) {
      const int chunk = wid * 4 + i;
      const int row = chunk * 8 + (lane >> 3);
      const int gslot = (lane & 7) ^ (row & 7);
      gload16(act + (size_t)row * 131072 + kb + gslot * 8, sA + chunk * 1024);
    }
#pragma unroll
    for (int i = 0; i < 2; ++i) {
      const int chunk = wid * 2 + i;
      const int row = chunk * 4 + (lane >> 4);
      const int gslot = (lane & 15) ^ (row & 7);
      gload16((const unsigned short*)(
                  ow + (size_t)(n0 + row) * 131072 + kb + gslot * 4),
              sB + chunk * 1024);
    }
    __syncthreads();
#pragma unroll
    for (int ks = 0; ks < 2; ++ks) {
      const int kbyte = ks * 64 + l16 * 16;
      const int sbase2 = ks * 8 + l16 * 2;
      bf16x8 av[4], bv[2];
#pragma unroll
      for (int f = 0; f < 4; ++f)
        av[f] = *(const bf16x8*)(sA + swz(wm * 64 + f * 16 + l15, kbyte));
#pragma unroll
      for (int f = 0; f < 2; ++f) {
        const int row = wn * 32 + f * 16 + l15;
        const int sw = row & 7;
        const unsigned char* pr = sB + row * 256;
        f32x4 lo = *(const f32x4*)(pr + ((sbase2 ^ sw) << 4));
        f32x4 hi = *(const f32x4*)(pr + (((sbase2 + 1) ^ sw) << 4));
        bf16x8 r;
        r[0] = (bf16)lo[0]; r[1] = (bf16)lo[1];
        r[2] = (bf16)lo[2]; r[3] = (bf16)lo[3];
        r[4] = (bf16)hi[0]; r[5] = (bf16)hi[1];
        r[6] = (bf16)hi[2]; r[7] = (bf16)hi[3];
        bv[f] = r;
      }
#pragma unroll
      for (int fm = 0; fm < 4; ++fm)
#pragma unroll
        for (int fn = 0; fn < 2; ++fn)
          acc[fm][fn] = MFMA(av[fm], bv[fn], acc[fm][fn]);
    }
  }

  float* __restrict__ P = partial + (size_t)blockIdx.y * (256 * 512);
  const int r4 = l16 * 4;
#pragma unroll
  for (int fn = 0; fn < 2; ++fn) {
    int col = n0 + wn * 32 + fn * 16 + l15;
#pragma unroll
    for (int fm = 0; fm < 4; ++fm) {
      int mb = wm * 64 + fm * 16 + r4;
#pragma unroll
      for (int j = 0; j < 4; ++j)
        P[(size_t)(mb + j) * 512 + col] = acc[fm][fn][j];
    }
  }
}

__global__ __launch_bounds__(128) void k_reduce(
    const float* __restrict__ partial,
    const float* __restrict__ ob,
    float* __restrict__ out)
{
  const int i4 = blockIdx.x * 128 + threadIdx.x;   // 32768 float4 groups
  f32x4 s = *(const f32x4*)(ob + ((i4 & 127) << 2));
#pragma unroll
  for (int ks = 0; ks < 32; ++ks)
    s += *(const f32x4*)(partial + (size_t)ks * 131072 + (size_t)i4 * 4);
  *(f32x4*)(out + (size_t)i4 * 4) = s;
}

// ---------------------------------------------------------------------------
extern "C" void kernel_launch(void* const* d_in, const int* in_sizes, int n_in,
                              void* d_out, int out_size, void* d_ws, size_t ws_size,
                              hipStream_t stream) {
  const float* x         = (const float*)d_in[0];
  const float* k_w       = (const float*)d_in[1];
  const float* k_b       = (const float*)d_in[2];
  const float* q_w       = (const float*)d_in[3];
  const float* q_b       = (const float*)d_in[4];
  const float* v_w       = (const float*)d_in[5];
  const float* v_b       = (const float*)d_in[6];
  const float* attn_bias = (const float*)d_in[7];
  const float* ln_g      = (const float*)d_in[8];
  const float* ln_b      = (const float*)d_in[9];
  const float* out_w     = (const float*)d_in[10];
  const float* out_b     = (const float*)d_in[11];
  float* out = (float*)d_out;

  char* ws = (char*)d_ws;
  // Layout:
  //   [0,64M)    k_t [B][H][S] bf16  (aliased by act in k_attn phase 2;
  //                                   per-block safe via barriers)
  //   [64,128M)  q_t [B][H][S] bf16  (aliased by partial in k_final2)
  //   [128,192M) v_o [B][S][H] bf16
  //   [192M+)    wc  [768][512] bf16 (pre-swizzled)
  unsigned short* k_t = (unsigned short*)(ws);
  unsigned short* q_t = (unsigned short*)(ws + 67108864);
  unsigned short* v_o = (unsigned short*)(ws + 134217728);
  unsigned short* wc  = (unsigned short*)(ws + 201326592);
  unsigned short* act = k_t;
  float* partial      = (float*)(ws + 67108864);

  k_convw<<<dim3(768), dim3(256), 0, stream>>>(k_w, q_w, v_w, wc);

  const int nwg = 3072;
  k_proj6<<<dim3(nwg), dim3(256), 0, stream>>>(
      x, wc, k_b, q_b, v_b, k_t, q_t, v_o, nwg);

  k_attn<<<dim3(256), dim3(1024), 0, stream>>>(
      k_t, q_t, v_o, attn_bias, ln_g, ln_b, act);

  k_final2<<<dim3(8, 32), dim3(512), 0, stream>>>(act, out_w, partial);
  k_reduce<<<dim3(256), dim3(128), 0, stream>>>(partial, out_b, out);
}

// Round 18
// 443.677 us; speedup vs baseline: 1.0599x; 1.0599x over previous
//
#include <hip/hip_runtime.h>
#include <hip/hip_bf16.h>
#include <math.h>

#define B_ 256
#define S_ 512
#define H_ 256
#define D_ 512

typedef __bf16 bf16;
typedef __bf16 bf16x8 __attribute__((ext_vector_type(8)));
typedef float  f32x4  __attribute__((ext_vector_type(4)));
typedef unsigned short u16x8 __attribute__((ext_vector_type(8)));
typedef unsigned short u16x4 __attribute__((ext_vector_type(4)));

#define MFMA(a, b, c) __builtin_amdgcn_mfma_f32_16x16x32_bf16((a), (b), (c), 0, 0, 0)

// 128B-row-stride bf16 tiles: XOR-swizzle 16B slot with row&7 (involution).
__device__ __forceinline__ int swz(int row, int kbyte) {
  return (row * 128 + kbyte) ^ ((row & 7) << 4);
}
__device__ __forceinline__ unsigned short bfbits(float f) {
  bf16 h = (bf16)f;
  union { bf16 b; unsigned short u; } c; c.b = h; return c.u;
}
__device__ __forceinline__ bf16x8 cvt8(const float* __restrict__ p) {
  f32x4 a = *(const f32x4*)p;
  f32x4 b = *(const f32x4*)(p + 4);
  bf16x8 r;
  r[0] = (bf16)a[0]; r[1] = (bf16)a[1]; r[2] = (bf16)a[2]; r[3] = (bf16)a[3];
  r[4] = (bf16)b[0]; r[5] = (bf16)b[1]; r[6] = (bf16)b[2]; r[7] = (bf16)b[3];
  return r;
}
__device__ __forceinline__ void gload16(const unsigned short* g, unsigned char* l) {
  __builtin_amdgcn_global_load_lds(
      (const __attribute__((address_space(1))) unsigned int*)g,
      (__attribute__((address_space(3))) unsigned int*)l, 16, 0, 0);
}

// ---------------------------------------------------------------------------
// Weight conversion. Writes wc PRE-SWIZZLED (rule #21) so linear
// global_load_lds staging + swz() LDS read is bank-conflict-free.
// ---------------------------------------------------------------------------
__global__ __launch_bounds__(256) void k_convw(
    const float* __restrict__ kw, const float* __restrict__ qw,
    const float* __restrict__ vw, unsigned short* __restrict__ wc)
{
  const int r = blockIdx.x;
  const float* src = (r < 256) ? kw + (size_t)r * 512
                   : (r < 512) ? qw + (size_t)(r - 256) * 512
                               : vw + (size_t)(r - 512) * 512;
#pragma unroll
  for (int q = 0; q < 2; ++q) {
    const int c = threadIdx.x * 2 + q;
    const int sc = (c & ~63) | (((((c >> 3) & 7) ^ (r & 7))) << 3) | (c & 7);
    wc[(size_t)r * 512 + c] = bfbits(src[sc]);
  }
}

// ---------------------------------------------------------------------------
// Kernel 1: QKV projection (r16 version: r13 structure + LDS-transpose
// epilogues for k/q and v — all stores coalesced u16x8).
// ---------------------------------------------------------------------------
__global__ __launch_bounds__(256, 2) void k_proj6(
    const float* __restrict__ x,
    const unsigned short* __restrict__ wc,
    const float* __restrict__ kbi, const float* __restrict__ qbi,
    const float* __restrict__ vbi,
    unsigned short* __restrict__ k_t, unsigned short* __restrict__ q_t,
    unsigned short* __restrict__ v_o, int nwg)
{
  __shared__ __align__(16) unsigned char sA[32768];  // 128 m x 16 fp32-slots
  __shared__ __align__(16) unsigned char sB[32768];  // 256 n x 64 k bf16

  const int o = blockIdx.x;
  const int cpx = nwg >> 3;
  const int a = (o & 7) * cpx + (o >> 3);
  const int mt = a / 3;
  const int region = a - mt * 3;
  const int m0 = mt * 128;
  const int w0 = region * 256;
  const float* __restrict__ Bi = (region == 0) ? kbi : (region == 1) ? qbi : vbi;

  const int tid = threadIdx.x;
  const int lane = tid & 63;
  const int wid = tid >> 6;
  const int wm = wid >> 1;
  const int wn = wid & 1;
  const int l15 = lane & 15;
  const int l16 = lane >> 4;
  const int lr8 = lane >> 3;
  const int lk8 = (lane & 7) << 3;
  const int ar4 = lane >> 4;
  const int aslot = l15;

  f32x4 acc[4][8];
#pragma unroll
  for (int i = 0; i < 4; ++i)
#pragma unroll
    for (int j = 0; j < 8; ++j) acc[i][j] = (f32x4){0.f, 0.f, 0.f, 0.f};

  for (int kt = 0; kt < 8; ++kt) {
    if (kt) __syncthreads();
#pragma unroll
    for (int i = 0; i < 8; ++i) {
      const int chunk = wid * 8 + i;
      const int arow = chunk * 4 + ar4;
      const int gslot = aslot ^ (arow & 7);
      gload16((const unsigned short*)(
                  x + (size_t)(m0 + arow) * D_ + kt * 64 + gslot * 4),
              sA + chunk * 1024);
    }
#pragma unroll
    for (int i = 0; i < 8; ++i) {
      const int chunk = wid * 8 + i;
      const int row = chunk * 8 + lr8;
      gload16(wc + (size_t)(w0 + row) * 512 + kt * 64 + lk8, sB + chunk * 1024);
    }
    __syncthreads();
#pragma unroll
    for (int ks = 0; ks < 2; ++ks) {
      const int kb2 = ks * 64 + (l16 << 4);
      const int sbase2 = ks * 8 + l16 * 2;
      bf16x8 av[4], bv[8];
#pragma unroll
      for (int f = 0; f < 4; ++f) {
        const int row = wm * 64 + f * 16 + l15;
        const int sw = row & 7;
        const unsigned char* pr = sA + row * 256;
        f32x4 lo = *(const f32x4*)(pr + ((sbase2 ^ sw) << 4));
        f32x4 hi = *(const f32x4*)(pr + (((sbase2 + 1) ^ sw) << 4));
        bf16x8 r;
        r[0] = (bf16)lo[0]; r[1] = (bf16)lo[1];
        r[2] = (bf16)lo[2]; r[3] = (bf16)lo[3];
        r[4] = (bf16)hi[0]; r[5] = (bf16)hi[1];
        r[6] = (bf16)hi[2]; r[7] = (bf16)hi[3];
        av[f] = r;
      }
#pragma unroll
      for (int f = 0; f < 8; ++f)
        bv[f] = *(const bf16x8*)(sB + swz(wn * 128 + f * 16 + l15, kb2));
#pragma unroll
      for (int fm = 0; fm < 4; ++fm)
#pragma unroll
        for (int fn = 0; fn < 8; ++fn)
          acc[fm][fn] = MFMA(av[fm], bv[fn], acc[fm][fn]);
    }
  }

  const int b = m0 >> 9;
  const int sbase = m0 & 511;

  if (region < 2) {
    // k/q: LDS transpose (sB dead) -> coalesced u16x8 stores along s.
    unsigned short* outp = (region == 0) ? k_t : q_t;
#pragma unroll
    for (int wmr = 0; wmr < 2; ++wmr) {
      __syncthreads();
      if (wm == wmr) {
#pragma unroll
        for (int fn = 0; fn < 8; ++fn) {
          const int hcol = wn * 128 + fn * 16 + l15;
          const float bias = Bi[hcol];
#pragma unroll
          for (int fm = 0; fm < 4; ++fm) {
            u16x4 ov;
#pragma unroll
            for (int j = 0; j < 4; ++j) ov[j] = bfbits(acc[fm][fn][j] + bias);
            const int byteoff = (fm * 32 + l16 * 8) ^ ((hcol & 7) << 4);
            *(u16x4*)(sB + hcol * 128 + byteoff) = ov;
          }
        }
      }
      __syncthreads();
#pragma unroll
      for (int c = 0; c < 8; ++c) {
        const int idx = c * 256 + tid;
        const int hcol = idx >> 3;
        const int sslot = idx & 7;
        const int byteoff = (sslot * 16) ^ ((hcol & 7) << 4);
        u16x8 v = *(const u16x8*)(sB + hcol * 128 + byteoff);
        *(u16x8*)(outp + (size_t)b * (H_ * S_) + (size_t)hcol * S_ +
                  sbase + wmr * 64 + sslot * 8) = v;
      }
    }
  } else {
    // v: LDS transpose (sB dead) -> coalesced u16x8 row stores.
    unsigned short* sT = (unsigned short*)sB;    // [32 rows][256 h]
#pragma unroll
    for (int fm = 0; fm < 4; ++fm) {
      __syncthreads();
#pragma unroll
      for (int fn = 0; fn < 8; ++fn) {
        const int hcol = wn * 128 + fn * 16 + l15;
        const float bias = Bi[hcol];
#pragma unroll
        for (int j = 0; j < 4; ++j) {
          const int tr = wm * 16 + l16 * 4 + j;
          sT[tr * 256 + hcol] = bfbits(acc[fm][fn][j] + bias);
        }
      }
      __syncthreads();
#pragma unroll
      for (int c = 0; c < 4; ++c) {
        const int idx = c * 256 + tid;
        const int tr = idx >> 5;
        const int hc = (idx & 31) * 8;
        const int s = sbase + (tr >> 4) * 64 + fm * 16 + (tr & 15);
        *(u16x8*)(v_o + (size_t)b * (S_ * H_) + (size_t)s * H_ + hc) =
            *(const u16x8*)(sT + tr * 256 + hc);
      }
    }
  }
}

// ---------------------------------------------------------------------------
// Kernel 2: fused scores+softmax+PV+bias+LN+GELU (r16/r10 staged-V version —
// measured optimum; V-direct (r17) and split (r11) both regressed).
// ---------------------------------------------------------------------------
__global__ __launch_bounds__(1024, 4) void k_attn(
    const unsigned short* __restrict__ k_t,
    const unsigned short* __restrict__ q_t,
    const unsigned short* __restrict__ v_o,
    const float* __restrict__ attn_bias,
    const float* __restrict__ lng, const float* __restrict__ lnb,
    unsigned short* __restrict__ act)
{
  __shared__ __align__(16) unsigned char sm[163840];
  unsigned char* sP = sm;                       // 128 KB P[256 g][256 h] (after p1)
  float* redm = (float*)(sm + 131072);          // [4][256]   (overlays sV0, p1 only)
  float* reds = (float*)(sm + 131072 + 4096);   // [4][256]
  float* lbuf = (float*)(sm + 147456);          // 8 KB       (overlays sV1, epilogue)

  const int tid = threadIdx.x;
  const int lane = tid & 63;
  const int wid = tid >> 6;           // 0..15
  const int l15 = lane & 15;
  const int l16 = lane >> 4;          // 0..3
  const int b = blockIdx.x;
  const int wh = wid >> 2;            // 0..3: h-quarter (p1) / s-quarter (p2)
  const int wq = wid & 3;             // 0..3: g-quarter

  const unsigned short* __restrict__ Kb = k_t + (size_t)b * (H_ * S_);
  const unsigned short* __restrict__ Qb = q_t + (size_t)b * (H_ * S_);
  const unsigned short* __restrict__ Vb = v_o + (size_t)b * (S_ * H_);

  // ---- Phase 1: S = K . Q^T, dbuf staging in sm[0:128K] ----
  const int srow8 = lane >> 3;
  const int scol16 = (lane & 7) ^ srow8;        // pre-swizzled source col

  auto stage1 = [&](int t, int buf) {           // 4 gload16/thread
#pragma unroll
    for (int i = 0; i < 2; ++i) {
      const int cb = wid * 2 + i;
      const int row = cb * 8 + srow8;
      gload16(Kb + (size_t)row * S_ + t * 64 + scol16 * 8,
              sm + buf * 65536 + cb * 1024);
      gload16(Qb + (size_t)row * S_ + t * 64 + scol16 * 8,
              sm + buf * 65536 + 32768 + cb * 1024);
    }
  };

  f32x4 acc1[4][4];
#pragma unroll
  for (int i = 0; i < 4; ++i)
#pragma unroll
    for (int j = 0; j < 4; ++j) acc1[i][j] = (f32x4){0.f, 0.f, 0.f, 0.f};

  stage1(0, 0);
  for (int t = 0; t < 8; ++t) {
    const int cur = t & 1;
    if (t < 7) stage1(t + 1, cur ^ 1);
    if (t < 7) asm volatile("s_waitcnt vmcnt(4)" ::: "memory");
    else       asm volatile("s_waitcnt vmcnt(0)" ::: "memory");
    __builtin_amdgcn_s_barrier();
    __builtin_amdgcn_sched_barrier(0);
    const unsigned char* sK = sm + cur * 65536;
    const unsigned char* sQ = sK + 32768;
#pragma unroll
    for (int ks = 0; ks < 2; ++ks) {
      const int kb2 = ks * 64 + l16 * 16;
      bf16x8 av[4], bv[4];
#pragma unroll
      for (int f = 0; f < 4; ++f)
        av[f] = *(const bf16x8*)(sK + swz(wh * 64 + f * 16 + l15, kb2));
#pragma unroll
      for (int f = 0; f < 4; ++f)
        bv[f] = *(const bf16x8*)(sQ + swz(wq * 64 + f * 16 + l15, kb2));
#pragma unroll
      for (int fm = 0; fm < 4; ++fm)
#pragma unroll
        for (int fn = 0; fn < 4; ++fn)
          acc1[fm][fn] = MFMA(av[fm], bv[fn], acc1[fm][fn]);
    }
    __builtin_amdgcn_sched_barrier(0);
    __builtin_amdgcn_s_barrier();               // reads consumed before overwrite
  }

  // ---- column softmax over h ----
  float cmax[4] = {-3.0e38f, -3.0e38f, -3.0e38f, -3.0e38f};
#pragma unroll
  for (int fm = 0; fm < 4; ++fm)
#pragma unroll
    for (int fn = 0; fn < 4; ++fn)
#pragma unroll
      for (int j = 0; j < 4; ++j) {
        acc1[fm][fn][j] *= 0.0625f;
        cmax[fn] = fmaxf(cmax[fn], acc1[fm][fn][j]);
      }
#pragma unroll
  for (int fn = 0; fn < 4; ++fn) {
    cmax[fn] = fmaxf(cmax[fn], __shfl_xor(cmax[fn], 16));
    cmax[fn] = fmaxf(cmax[fn], __shfl_xor(cmax[fn], 32));
  }
  if (lane < 16) {
#pragma unroll
    for (int fn = 0; fn < 4; ++fn)
      redm[wh * 256 + wq * 64 + fn * 16 + lane] = cmax[fn];
  }
  __syncthreads();
  float gmax[4];
#pragma unroll
  for (int fn = 0; fn < 4; ++fn) {
    const int c = wq * 64 + fn * 16 + l15;
    gmax[fn] = fmaxf(fmaxf(redm[c], redm[256 + c]),
                     fmaxf(redm[512 + c], redm[768 + c]));
  }
  float csum[4] = {0.f, 0.f, 0.f, 0.f};
#pragma unroll
  for (int fm = 0; fm < 4; ++fm)
#pragma unroll
    for (int fn = 0; fn < 4; ++fn)
#pragma unroll
      for (int j = 0; j < 4; ++j) {
        float p = __expf(acc1[fm][fn][j] - gmax[fn]);
        acc1[fm][fn][j] = p;
        csum[fn] += p;
      }
#pragma unroll
  for (int fn = 0; fn < 4; ++fn) {
    csum[fn] += __shfl_xor(csum[fn], 16);
    csum[fn] += __shfl_xor(csum[fn], 32);
  }
  if (lane < 16) {
#pragma unroll
    for (int fn = 0; fn < 4; ++fn)
      reds[wh * 256 + wq * 64 + fn * 16 + lane] = csum[fn];
  }
  __syncthreads();
  float gi[4];
#pragma unroll
  for (int fn = 0; fn < 4; ++fn) {
    const int c = wq * 64 + fn * 16 + l15;
    gi[fn] = 1.0f / (reds[c] + reds[256 + c] + reds[512 + c] + reds[768 + c]);
  }

  // ---- write P[g][h] bf16, swizzled, over the (dead) staging buffers ----
#pragma unroll
  for (int fn = 0; fn < 4; ++fn) {
    const int g = wq * 64 + fn * 16 + l15;
#pragma unroll
    for (int fm = 0; fm < 4; ++fm) {
      const int h0 = wh * 64 + fm * 16 + l16 * 4;
      u16x4 pv;
#pragma unroll
      for (int j = 0; j < 4; ++j) pv[j] = bfbits(acc1[fm][fn][j] * gi[fn]);
      *(u16x4*)(sP + ((g * 512 + h0 * 2) ^ ((g & 7) << 4))) = pv;
    }
  }
  __syncthreads();                              // P visible to all

  // ---- Phase 2: out = V . P^T, dbuf V staging, pipelined ----
  const int vrow = tid >> 2;                        // 0..255
  const int vcol16 = (tid & 3) ^ ((vrow >> 1) & 3); // pre-swizzled 16B col

  auto stageV = [&](int t) {                    // 1 gload16/thread
    const int so_ = t >> 3, kh_ = t & 7;
    gload16(Vb + (size_t)(so_ * 256 + vrow) * H_ + kh_ * 32 + vcol16 * 8,
            sm + 131072 + (t & 1) * 16384 + wid * 1024);
  };

  f32x4 acc2[4][4];
  stageV(0);
  for (int t = 0; t < 16; ++t) {
    const int so = t >> 3, kh = t & 7, cur = t & 1;
    if (kh == 0) {
#pragma unroll
      for (int i = 0; i < 4; ++i)
#pragma unroll
        for (int j = 0; j < 4; ++j) acc2[i][j] = (f32x4){0.f, 0.f, 0.f, 0.f};
    }
    if (t < 15) stageV(t + 1);
    if (t < 15) asm volatile("s_waitcnt vmcnt(1)" ::: "memory");
    else        asm volatile("s_waitcnt vmcnt(0)" ::: "memory");
    __builtin_amdgcn_s_barrier();
    __builtin_amdgcn_sched_barrier(0);
    const unsigned char* sV = sm + 131072 + cur * 16384;
    bf16x8 av[4], bv[4];
#pragma unroll
    for (int f = 0; f < 4; ++f) {
      const int rl = wh * 64 + f * 16 + l15;
      av[f] = *(const bf16x8*)(sV + rl * 64 + ((l16 ^ ((rl >> 1) & 3)) << 4));
    }
#pragma unroll
    for (int fn = 0; fn < 4; ++fn) {
      const int g = wq * 64 + fn * 16 + l15;
      bv[fn] = *(const bf16x8*)(
          sP + ((g * 512 + kh * 64 + l16 * 16) ^ ((g & 7) << 4)));
    }
#pragma unroll
    for (int f = 0; f < 4; ++f)
#pragma unroll
      for (int fn = 0; fn < 4; ++fn)
        acc2[f][fn] = MFMA(av[f], bv[fn], acc2[f][fn]);
    __builtin_amdgcn_sched_barrier(0);

    if (kh == 7) {
      // epilogue: +bias, LN over g, GELU, store. lbuf overlays sV1 (consumed).
      __syncthreads();
#pragma unroll
      for (int f = 0; f < 4; ++f) {
#pragma unroll
        for (int j = 0; j < 4; ++j) {
          const int rloc = wh * 64 + f * 16 + l16 * 4 + j;
          const int s = so * 256 + rloc;
          float ps = 0.f, psq = 0.f;
#pragma unroll
          for (int fn = 0; fn < 4; ++fn) {
            const int g = wq * 64 + fn * 16 + l15;
            float vv = acc2[f][fn][j] + attn_bias[(size_t)s * H_ + g];
            acc2[f][fn][j] = vv;
            ps += vv; psq += vv * vv;
          }
          ps += __shfl_xor(ps, 1);  psq += __shfl_xor(psq, 1);
          ps += __shfl_xor(ps, 2);  psq += __shfl_xor(psq, 2);
          ps += __shfl_xor(ps, 4);  psq += __shfl_xor(psq, 4);
          ps += __shfl_xor(ps, 8);  psq += __shfl_xor(psq, 8);
          if (l15 == 0) {
            lbuf[wq * 256 + rloc] = ps;
            lbuf[1024 + wq * 256 + rloc] = psq;
          }
        }
      }
      __syncthreads();
#pragma unroll
      for (int f = 0; f < 4; ++f) {
#pragma unroll
        for (int j = 0; j < 4; ++j) {
          const int rloc = wh * 64 + f * 16 + l16 * 4 + j;
          const int s = so * 256 + rloc;
          float sum = lbuf[rloc] + lbuf[256 + rloc] +
                      lbuf[512 + rloc] + lbuf[768 + rloc];
          float sq  = lbuf[1024 + rloc] + lbuf[1280 + rloc] +
                      lbuf[1536 + rloc] + lbuf[1792 + rloc];
          float mu = sum * (1.f / H_);
          float var = sq * (1.f / H_) - mu * mu;
          float rstd = rsqrtf(var + 1e-5f);
#pragma unroll
          for (int fn = 0; fn < 4; ++fn) {
            const int g = wq * 64 + fn * 16 + l15;
            float xv = (acc2[f][fn][j] - mu) * rstd * lng[g] + lnb[g];
            float y = 0.5f * xv * (1.f + erff(xv * 0.70710678118654752f));
            act[(size_t)b * (S_ * H_) + (size_t)s * H_ + g] = bfbits(y);
          }
        }
      }
      __syncthreads();                          // lbuf reads done before reuse
    } else {
      __builtin_amdgcn_s_barrier();             // sV[cur] consumed everywhere
    }
  }
}

// ---------------------------------------------------------------------------
// Kernel 3: final GEMM, split-K (unchanged from r13 — near HBM floor).
// ---------------------------------------------------------------------------
__global__ __launch_bounds__(512, 4) void k_final2(
    const unsigned short* __restrict__ act,
    const float* __restrict__ ow,
    float* __restrict__ partial)
{
  __shared__ __align__(16) unsigned char sA[32768];  // 256 m x 8 bf16-slots
  __shared__ __align__(16) unsigned char sB[16384];  // 64 n x 16 fp32-slots

  const int tid = threadIdx.x;
  const int lane = tid & 63;
  const int wid = tid >> 6;
  const int wm = wid >> 1;
  const int wn = wid & 1;
  const int l15 = lane & 15;
  const int l16 = lane >> 4;
  const int n0 = blockIdx.x * 64;
  const size_t k0 = (size_t)blockIdx.y * 4096;

  f32x4 acc[4][2];
#pragma unroll
  for (int i = 0; i < 4; ++i)
#pragma unroll
    for (int j = 0; j < 2; ++j) acc[i][j] = (f32x4){0.f, 0.f, 0.f, 0.f};

  for (int kt = 0; kt < 64; ++kt) {
    const size_t kb = k0 + kt * 64;
    if (kt) __syncthreads();
#pragma unroll
    for (int i = 0; i < 4; ++i) {
      const int chunk = wid * 4 + i;
      const int row = chunk * 8 + (lane >> 3);
      const int gslot = (lane & 7) ^ (row & 7);
      gload16(act + (size_t)row * 131072 + kb + gslot * 8, sA + chunk * 1024);
    }
#pragma unroll
    for (int i = 0; i < 2; ++i) {
      const int chunk = wid * 2 + i;
      const int row = chunk * 4 + (lane >> 4);
      const int gslot = (lane & 15) ^ (row & 7);
      gload16((const unsigned short*)(
                  ow + (size_t)(n0 + row) * 131072 + kb + gslot * 4),
              sB + chunk * 1024);
    }
    __syncthreads();
#pragma unroll
    for (int ks = 0; ks < 2; ++ks) {
      const int kbyte = ks * 64 + l16 * 16;
      const int sbase2 = ks * 8 + l16 * 2;
      bf16x8 av[4], bv[2];
#pragma unroll
      for (int f = 0; f < 4; ++f)
        av[f] = *(const bf16x8*)(sA + swz(wm * 64 + f * 16 + l15, kbyte));
#pragma unroll
      for (int f = 0; f < 2; ++f) {
        const int row = wn * 32 + f * 16 + l15;
        const int sw = row & 7;
        const unsigned char* pr = sB + row * 256;
        f32x4 lo = *(const f32x4*)(pr + ((sbase2 ^ sw) << 4));
        f32x4 hi = *(const f32x4*)(pr + (((sbase2 + 1) ^ sw) << 4));
        bf16x8 r;
        r[0] = (bf16)lo[0]; r[1] = (bf16)lo[1];
        r[2] = (bf16)lo[2]; r[3] = (bf16)lo[3];
        r[4] = (bf16)hi[0]; r[5] = (bf16)hi[1];
        r[6] = (bf16)hi[2]; r[7] = (bf16)hi[3];
        bv[f] = r;
      }
#pragma unroll
      for (int fm = 0; fm < 4; ++fm)
#pragma unroll
        for (int fn = 0; fn < 2; ++fn)
          acc[fm][fn] = MFMA(av[fm], bv[fn], acc[fm][fn]);
    }
  }

  float* __restrict__ P = partial + (size_t)blockIdx.y * (256 * 512);
  const int r4 = l16 * 4;
#pragma unroll
  for (int fn = 0; fn < 2; ++fn) {
    int col = n0 + wn * 32 + fn * 16 + l15;
#pragma unroll
    for (int fm = 0; fm < 4; ++fm) {
      int mb = wm * 64 + fm * 16 + r4;
#pragma unroll
      for (int j = 0; j < 4; ++j)
        P[(size_t)(mb + j) * 512 + col] = acc[fm][fn][j];
    }
  }
}

__global__ __launch_bounds__(128) void k_reduce(
    const float* __restrict__ partial,
    const float* __restrict__ ob,
    float* __restrict__ out)
{
  const int i4 = blockIdx.x * 128 + threadIdx.x;   // 32768 float4 groups
  f32x4 s = *(const f32x4*)(ob + ((i4 & 127) << 2));
#pragma unroll
  for (int ks = 0; ks < 32; ++ks)
    s += *(const f32x4*)(partial + (size_t)ks * 131072 + (size_t)i4 * 4);
  *(f32x4*)(out + (size_t)i4 * 4) = s;
}

// ---------------------------------------------------------------------------
extern "C" void kernel_launch(void* const* d_in, const int* in_sizes, int n_in,
                              void* d_out, int out_size, void* d_ws, size_t ws_size,
                              hipStream_t stream) {
  const float* x         = (const float*)d_in[0];
  const float* k_w       = (const float*)d_in[1];
  const float* k_b       = (const float*)d_in[2];
  const float* q_w       = (const float*)d_in[3];
  const float* q_b       = (const float*)d_in[4];
  const float* v_w       = (const float*)d_in[5];
  const float* v_b       = (const float*)d_in[6];
  const float* attn_bias = (const float*)d_in[7];
  const float* ln_g      = (const float*)d_in[8];
  const float* ln_b      = (const float*)d_in[9];
  const float* out_w     = (const float*)d_in[10];
  const float* out_b     = (const float*)d_in[11];
  float* out = (float*)d_out;

  char* ws = (char*)d_ws;
  // Layout:
  //   [0,64M)    k_t [B][H][S] bf16  (aliased by act in k_attn phase 2;
  //                                   per-block safe via barriers)
  //   [64,128M)  q_t [B][H][S] bf16  (aliased by partial in k_final2)
  //   [128,192M) v_o [B][S][H] bf16
  //   [192M+)    wc  [768][512] bf16 (pre-swizzled)
  unsigned short* k_t = (unsigned short*)(ws);
  unsigned short* q_t = (unsigned short*)(ws + 67108864);
  unsigned short* v_o = (unsigned short*)(ws + 134217728);
  unsigned short* wc  = (unsigned short*)(ws + 201326592);
  unsigned short* act = k_t;
  float* partial      = (float*)(ws + 67108864);

  k_convw<<<dim3(768), dim3(256), 0, stream>>>(k_w, q_w, v_w, wc);

  const int nwg = 3072;
  k_proj6<<<dim3(nwg), dim3(256), 0, stream>>>(
      x, wc, k_b, q_b, v_b, k_t, q_t, v_o, nwg);

  k_attn<<<dim3(256), dim3(1024), 0, stream>>>(
      k_t, q_t, v_o, attn_bias, ln_g, ln_b, act);

  k_final2<<<dim3(8, 32), dim3(512), 0, stream>>>(act, out_w, partial);
  k_reduce<<<dim3(256), dim3(128), 0, stream>>>(partial, out_b, out);
}